// Round 3
// baseline (2942.428 us; speedup 1.0000x reference)
//
#include <hip/hip_runtime.h>

// Graphormer encoder — single persistent mega-kernel, MANUAL grid barrier.
// R11: R10's cooperative launch replaced by a device-scope atomic ticket
// barrier in workspace (cooperative launch silently failed -> zero output).
// 512 blocks x 256 thr; launch_bounds(256,2) caps VGPR<=256 and 32KB LDS
// allows 5 blocks/CU => all 512 blocks co-resident under a PLAIN launch, so
// the barrier cannot deadlock. Barrier words re-zeroed per invocation by a
// tiny init kernel (workspace is poisoned between iterations).

#define NG   64
#define NP   31
#define NORI 1984
#define NT   2048
#define DIM  512
#define NHD  8
#define DKH  64
#define FFD  2048
#define NLAY 4
#define NFEA 32
#define GRID 512

typedef __attribute__((ext_vector_type(8))) short short8;
typedef __attribute__((ext_vector_type(4))) float floatx4;

__device__ __forceinline__ unsigned short f2bf(float f) {
    union { float f; unsigned u; } v; v.f = f;
    unsigned r = v.u + 0x7fffu + ((v.u >> 16) & 1u);
    return (unsigned short)(r >> 16);
}
__device__ __forceinline__ float bf2f(unsigned short u) {
    union { unsigned u; float f; } v; v.u = ((unsigned)u) << 16;
    return v.f;
}

struct MP {
    const float* x; const int* sp; const int* degrees;
    const float* init_W; const float* init_b; const float* cent_emb;
    const float* db; const float* vbias;
    const float* Wq; const float* Wk; const float* Wv;
    const float* bq; const float* bk; const float* bv;
    const float* Wo; const float* bo; const float* W1; const float* b1;
    const float* W2; const float* b2;
    float* h; unsigned short* hn; unsigned short* o; unsigned short* qkv;
    float* Bg;
    unsigned short* Wqkv_t; unsigned short* Wo_t; unsigned short* W1_t; unsigned short* W2_t;
    float* bqkv;
    unsigned* bar;
    float* out;
};

// ---------------------------------------------------------------- manual grid barrier
// bar[0] = arrive counter, bar[1] = generation. Agent-scope atomics + fences.
__device__ __forceinline__ void gbar(unsigned* bar)
{
    __syncthreads();
    if (threadIdx.x == 0) {
        __threadfence();                                    // release prior writes
        unsigned g = __hip_atomic_load(bar + 1, __ATOMIC_ACQUIRE, __HIP_MEMORY_SCOPE_AGENT);
        unsigned t = __hip_atomic_fetch_add(bar, 1u, __ATOMIC_ACQ_REL, __HIP_MEMORY_SCOPE_AGENT);
        if (t == GRID - 1u) {
            __hip_atomic_store(bar, 0u, __ATOMIC_RELAXED, __HIP_MEMORY_SCOPE_AGENT);
            __threadfence();
            __hip_atomic_fetch_add(bar + 1, 1u, __ATOMIC_ACQ_REL, __HIP_MEMORY_SCOPE_AGENT);
        } else {
            while (__hip_atomic_load(bar + 1, __ATOMIC_ACQUIRE, __HIP_MEMORY_SCOPE_AGENT) == g)
                __builtin_amdgcn_s_sleep(2);
        }
        __threadfence();                                    // acquire
    }
    __syncthreads();
}

__global__ void bar_init(unsigned* bar) { bar[0] = 0u; bar[1] = 0u; }

// ---------------------------------------------------------------- prep units
__device__ __forceinline__ void prep_inith_unit(const MP& p, int n, char* smem)
{
    int tid = threadIdx.x;
    if (n >= NT) {               // build_B: one unit per graph
        int g = n - NT;
        float vb = p.vbias[0];
        for (int e = tid; e < 1024; e += 256) {
            int i = e >> 5, j = e & 31;
            float v;
            if (i == j) v = p.db[0];
            else if (i < NP && j < NP) {
                int s = p.sp[(size_t)(g * NP + i) * NORI + g * NP + j];
                v = p.db[s < 100 ? s : 100];
            } else v = vb;
            p.Bg[(size_t)g * 1024 + e] = v;
        }
        return;
    }
    float* xs = (float*)smem;
    if (n < NORI && tid < NFEA) xs[tid] = p.x[(size_t)n * NFEA + tid];
    __syncthreads();
    int deg = p.degrees[n]; if (deg > 100) deg = 100;
    for (int d = tid; d < DIM; d += 256) {
        float v = p.cent_emb[(size_t)deg * DIM + d];
        if (n < NORI) {
            float acc = p.init_b[d];
            #pragma unroll
            for (int k = 0; k < NFEA; ++k) acc += xs[k] * p.init_W[(size_t)k * DIM + d];
            v += acc;
        }
        p.h[(size_t)n * DIM + d] = v;
    }
}

__device__ __forceinline__ void prep_qkv_unit(const MP& p, int tile, char* smem)
{
    if (tile >= 3072) {          // bias part
        int idx = (tile - 3072) * 256 + threadIdx.x;
        if (idx < NLAY * 1536) {
            int l = idx / 1536, c = idx % 1536;
            int which = c >> 9, cc = c & 511;
            const float* b = (which == 0) ? p.bq : (which == 1) ? p.bk : p.bv;
            p.bqkv[idx] = b[(size_t)l * 512 + cc];
        }
        return;
    }
    float (*tl)[33] = (float(*)[33])smem;
    int slice = tile >> 5;
    int tloc = tile & 31;
    int dt = tloc >> 1, kt = tloc & 1;
    int l = slice / 24; int rem = slice % 24; int which = rem >> 3; int hh = rem & 7;
    const float* W = (which == 0) ? p.Wq : (which == 1) ? p.Wk : p.Wv;
    const float* in = W + (size_t)(l * 8 + hh) * DIM * DKH;
    int tr = threadIdx.x >> 5, tc = threadIdx.x & 31;
    #pragma unroll
    for (int pp = 0; pp < 4; ++pp)
        tl[tr + pp * 8][tc] = in[(size_t)(dt * 32 + tr + pp * 8) * DKH + kt * 32 + tc];
    __syncthreads();
    unsigned short* out = p.Wqkv_t + ((size_t)l * 1536 + which * 512 + hh * 64 + kt * 32) * DIM + dt * 32;
    #pragma unroll
    for (int pp = 0; pp < 4; ++pp)
        out[(size_t)(tr + pp * 8) * DIM + tc] = f2bf(tl[tc][tr + pp * 8]);
}

__device__ __forceinline__ void prep_w_unit(const MP& p, int id, char* smem)
{
    float (*tl)[33] = (float(*)[33])smem;
    const float* in; unsigned short* outp; int R, C, l, rt, ct;
    if (id < 1024) {
        l = id >> 8; int t = id & 255; rt = t >> 4; ct = t & 15;
        in = p.Wo; outp = p.Wo_t; R = 512; C = 512;
    } else if (id < 5120) {
        int t2 = id - 1024; l = t2 >> 10; int t = t2 & 1023; rt = t >> 6; ct = t & 63;
        in = p.W1; outp = p.W1_t; R = 512; C = 2048;
    } else {
        int t2 = id - 5120; l = t2 >> 10; int t = t2 & 1023; rt = t >> 4; ct = t & 15;
        in = p.W2; outp = p.W2_t; R = 2048; C = 512;
    }
    const float* ip = in + (size_t)l * R * C;
    unsigned short* op = outp + (size_t)l * R * C;
    int r0 = rt * 32, c0 = ct * 32;
    int tr = threadIdx.x >> 5, tc = threadIdx.x & 31;
    #pragma unroll
    for (int pp = 0; pp < 4; ++pp)
        tl[tr + pp * 8][tc] = ip[(size_t)(r0 + tr + pp * 8) * C + c0 + tc];
    __syncthreads();
    #pragma unroll
    for (int pp = 0; pp < 4; ++pp)
        op[(size_t)(c0 + tr + pp * 8) * R + r0 + tc] = f2bf(tl[tc][tr + pp * 8]);
}

// ---------------------------------------------------------------- layernorm stage
__device__ void stage_ln(const MP& p, int row0, int nrows, bool docopy, char* smem)
{
    float* red = (float*)smem;
    int tid = threadIdx.x;
    int wave = tid >> 6;
    for (int r = blockIdx.x; r < nrows; r += GRID) {
        int n = row0 + r;
        const float* row = p.h + (size_t)n * DIM;
        float v0 = row[tid], v1 = row[tid + 256];
        float s = v0 + v1;
        float sq = v0 * v0 + v1 * v1;
        #pragma unroll
        for (int off = 32; off > 0; off >>= 1) {
            s  += __shfl_down(s, off);
            sq += __shfl_down(sq, off);
        }
        if ((tid & 63) == 0) { red[wave] = s; red[4 + wave] = sq; }
        __syncthreads();
        float ts  = red[0] + red[1] + red[2] + red[3];
        float tsq = red[4] + red[5] + red[6] + red[7];
        __syncthreads();                      // red reused next iteration
        float m   = ts * (1.0f / DIM);
        float var = tsq * (1.0f / DIM) - m * m;
        float inv = rsqrtf(var + 1e-5f);
        p.hn[(size_t)n * DIM + tid]       = f2bf((v0 - m) * inv);
        p.hn[(size_t)n * DIM + tid + 256] = f2bf((v1 - m) * inv);
        if (docopy) {                         // seed d_out with the residual h
            p.out[(size_t)(n - NORI) * DIM + tid]       = v0;
            p.out[(size_t)(n - NORI) * DIM + tid + 256] = v1;
        }
    }
}

// ---------------------------------------------------------------- gemm128 stage (m97 structure)
__device__ void stage_gemm128(const unsigned short* __restrict__ A,
    const unsigned short* __restrict__ Bt, const float* __restrict__ bias,
    void* __restrict__ out, int Nfull, int K, int flags, int P, int C,
    int SPLITK, char* smem)
{
    unsigned short* Asl = (unsigned short*)smem;
    unsigned short* Bsl = Asl + 128 * 64;
    int ntiles = P * C * SPLITK;
    int tid = threadIdx.x;
    int wave = tid >> 6, lane = tid & 63;
    int quad = lane >> 4, m16 = lane & 15;
    int mw = (wave >> 1) * 64, nw = (wave & 1) * 64;
    int lr = lane >> 3;
    int srcswz = ((lane & 7) ^ lr) << 3;
    int rdswz = (m16 & 7) << 4;
    int kslice = K / SPLITK;
    for (int id = blockIdx.x; id < ntiles; id += GRID) {
        int xcd = id & 7, t = id >> 3, Gp = P >> 3;
        int by = xcd + 8 * (t % Gp);
        int r2 = t / Gp;
        int bx = r2 % C;
        int bz = r2 / C;
        int row0 = by * 128, col0 = bx * 128;
        if ((flags & 4) && col0 < 512 && row0 + 128 <= NORI) continue;
        int kbeg = bz * kslice;
        const unsigned short* Abase = A + (size_t)row0 * K;
        const unsigned short* Bbase = Bt + (size_t)col0 * K;
        floatx4 acc[4][4] = {};
        __syncthreads();
        for (int k0 = kbeg; k0 < kbeg + kslice; k0 += 64) {
            #pragma unroll
            for (int pp = 0; pp < 4; ++pp) {
                int chunk = wave * 4 + pp;
                int r = chunk * 8 + lr;
                __builtin_amdgcn_global_load_lds(
                    (const __attribute__((address_space(1))) unsigned int*)
                        (Abase + (size_t)r * K + k0 + srcswz),
                    (__attribute__((address_space(3))) unsigned int*)
                        (Asl + chunk * 512 + lane * 8), 16, 0, 0);
                __builtin_amdgcn_global_load_lds(
                    (const __attribute__((address_space(1))) unsigned int*)
                        (Bbase + (size_t)r * K + k0 + srcswz),
                    (__attribute__((address_space(3))) unsigned int*)
                        (Bsl + chunk * 512 + lane * 8), 16, 0, 0);
            }
            __syncthreads();
            #pragma unroll
            for (int ks = 0; ks < 64; ks += 32) {
                short8 a[4], b[4];
                int cb = (ks + quad * 8) * 2;
                #pragma unroll
                for (int mi = 0; mi < 4; ++mi)
                    a[mi] = *(const short8*)((const char*)Asl +
                            (mw + mi * 16 + m16) * 128 + (cb ^ rdswz));
                #pragma unroll
                for (int ni = 0; ni < 4; ++ni)
                    b[ni] = *(const short8*)((const char*)Bsl +
                            (nw + ni * 16 + m16) * 128 + (cb ^ rdswz));
                #pragma unroll
                for (int mi = 0; mi < 4; ++mi)
                    #pragma unroll
                    for (int ni = 0; ni < 4; ++ni)
                        acc[mi][ni] = __builtin_amdgcn_mfma_f32_16x16x32_bf16(
                            a[mi], b[ni], acc[mi][ni], 0, 0, 0);
            }
            __syncthreads();
        }
        if (SPLITK == 1) {
            int do_relu = flags & 1, out_bf = flags & 2;
            #pragma unroll
            for (int mi = 0; mi < 4; ++mi) {
                #pragma unroll
                for (int ni = 0; ni < 4; ++ni) {
                    int col = col0 + nw + ni * 16 + m16;
                    float bval = bias[col];
                    #pragma unroll
                    for (int rr = 0; rr < 4; ++rr) {
                        int row = row0 + mw + mi * 16 + quad * 4 + rr;
                        float v = acc[mi][ni][rr] + bval;
                        if (do_relu) v = fmaxf(v, 0.0f);
                        if (out_bf) ((unsigned short*)out)[(size_t)row * Nfull + col] = f2bf(v);
                        else        ((float*)out)[(size_t)row * Nfull + col] = v;
                    }
                }
            }
        } else {
            float* ofp = (float*)out;
            float bscale = (bz == 0) ? 1.0f : 0.0f;
            #pragma unroll
            for (int mi = 0; mi < 4; ++mi) {
                #pragma unroll
                for (int ni = 0; ni < 4; ++ni) {
                    int col = col0 + nw + ni * 16 + m16;
                    float bval = bias[col] * bscale;
                    #pragma unroll
                    for (int rr = 0; rr < 4; ++rr) {
                        int row = row0 + mw + mi * 16 + quad * 4 + rr;
                        atomicAdd(&ofp[(size_t)row * Nfull + col], acc[mi][ni][rr] + bval);
                    }
                }
            }
        }
    }
}

// ---------------------------------------------------------------- gemm64 stage (small M)
__device__ void stage_gemm64(const unsigned short* __restrict__ A,
    const unsigned short* __restrict__ Bt, const float* __restrict__ bias,
    void* __restrict__ out, int Nfull, int K, int moff, int flags,
    int P, int C, int SPLITK, int orow, char* smem)
{
    unsigned short* Asl = (unsigned short*)smem;          // 64*72
    unsigned short* Bsl = Asl + 64 * 72;
    int ntiles = P * C * SPLITK;
    int tid = threadIdx.x;
    int wave = tid >> 6, lane = tid & 63;
    int quad = lane >> 4, m16 = lane & 15;
    int mw = (wave >> 1) * 32, nw = (wave & 1) * 32;
    int kslice = K / SPLITK;
    for (int id = blockIdx.x; id < ntiles; id += GRID) {
        int by, bx, bz;
        if (P >= 8) {
            int xcd = id & 7, t = id >> 3, Gp = P >> 3;
            by = xcd + 8 * (t % Gp);
            int r2 = t / Gp;
            bx = r2 % C;
            bz = r2 / C;
        } else {
            by = id % P; int r2 = id / P; bx = r2 % C; bz = r2 / C;
        }
        int row0 = moff + by * 64, col0 = bx * 64;
        if ((flags & 4) && col0 < 512 && row0 < NORI) continue;
        int kbeg = bz * kslice;
        floatx4 acc[2][2] = {};
        __syncthreads();
        for (int k0 = kbeg; k0 < kbeg + kslice; k0 += 64) {
            #pragma unroll
            for (int pp = 0; pp < 2; ++pp) {
                int idx = (pp * 256 + tid) * 8;
                int r = idx >> 6, kk = idx & 63;
                *(float4*)(Asl + r * 72 + kk) =
                    *(const float4*)(A + (size_t)(row0 + r) * K + k0 + kk);
                *(float4*)(Bsl + r * 72 + kk) =
                    *(const float4*)(Bt + (size_t)(col0 + r) * K + k0 + kk);
            }
            __syncthreads();
            #pragma unroll
            for (int ks = 0; ks < 64; ks += 32) {
                short8 a[2], b[2];
                #pragma unroll
                for (int mi = 0; mi < 2; ++mi)
                    a[mi] = *(const short8*)(Asl + (mw + mi * 16 + m16) * 72 + ks + quad * 8);
                #pragma unroll
                for (int ni = 0; ni < 2; ++ni)
                    b[ni] = *(const short8*)(Bsl + (nw + ni * 16 + m16) * 72 + ks + quad * 8);
                #pragma unroll
                for (int mi = 0; mi < 2; ++mi)
                    #pragma unroll
                    for (int ni = 0; ni < 2; ++ni)
                        acc[mi][ni] = __builtin_amdgcn_mfma_f32_16x16x32_bf16(
                            a[mi], b[ni], acc[mi][ni], 0, 0, 0);
            }
            __syncthreads();
        }
        if (SPLITK == 1) {
            int do_relu = flags & 1, out_bf = flags & 2;
            #pragma unroll
            for (int mi = 0; mi < 2; ++mi) {
                #pragma unroll
                for (int ni = 0; ni < 2; ++ni) {
                    int col = col0 + nw + ni * 16 + m16;
                    float bval = bias[col];
                    #pragma unroll
                    for (int rr = 0; rr < 4; ++rr) {
                        int row = row0 + mw + mi * 16 + quad * 4 + rr;
                        float v = acc[mi][ni][rr] + bval;
                        if (do_relu) v = fmaxf(v, 0.0f);
                        if (out_bf) ((unsigned short*)out)[(size_t)(row - orow) * Nfull + col] = f2bf(v);
                        else        ((float*)out)[(size_t)(row - orow) * Nfull + col] = v;
                    }
                }
            }
        } else {
            float* ofp = (float*)out;
            float bscale = (bz == 0) ? 1.0f : 0.0f;
            #pragma unroll
            for (int mi = 0; mi < 2; ++mi) {
                #pragma unroll
                for (int ni = 0; ni < 2; ++ni) {
                    int col = col0 + nw + ni * 16 + m16;
                    float bval = bias[col] * bscale;
                    #pragma unroll
                    for (int rr = 0; rr < 4; ++rr) {
                        int row = row0 + mw + mi * 16 + quad * 4 + rr;
                        atomicAdd(&ofp[(size_t)(row - orow) * Nfull + col],
                                  acc[mi][ni][rr] + bval);
                    }
                }
            }
        }
    }
}

// ---------------------------------------------------------------- attention stage (layers 0..2)
__device__ void stage_attn(const MP& p, char* smem)
{
    float (*Qs)[65] = (float(*)[65])(smem);
    float (*Ks)[65] = (float(*)[65])(smem + 8320);
    float (*Vs)[65] = (float(*)[65])(smem + 16640);
    float (*S)[33]  = (float(*)[33])(smem + 24960);
    int tid = threadIdx.x;
    int i = tid >> 3;
    int c0 = (tid & 7) * 8;
    for (int u = blockIdx.x; u < NG * NHD; u += GRID) {
        int g = u >> 3, hh = u & 7;
        __syncthreads();
        int gn = (i < NP) ? g * NP + i : NORI + g;
        const unsigned short* base = p.qkv + (size_t)gn * 1536 + hh * DKH;
        short8 qv = *(const short8*)(base + c0);
        short8 kv = *(const short8*)(base + 512 + c0);
        short8 vv = *(const short8*)(base + 1024 + c0);
        #pragma unroll
        for (int j = 0; j < 8; ++j) {
            Qs[i][c0 + j] = bf2f((unsigned short)qv[j]);
            Ks[i][c0 + j] = bf2f((unsigned short)kv[j]);
            Vs[i][c0 + j] = bf2f((unsigned short)vv[j]);
        }
        __syncthreads();
        const float scale = 0.125f;
        #pragma unroll
        for (int e = 0; e < 4; ++e) {
            int idx = tid + e * 256;
            int si = idx >> 5, sj = idx & 31;
            float dot = 0.0f;
            #pragma unroll
            for (int k = 0; k < DKH; ++k) dot += Qs[si][k] * Ks[sj][k];
            S[si][sj] = dot * scale + p.Bg[(size_t)g * 1024 + si * 32 + sj];
        }
        __syncthreads();
        if (tid < 32) {
            float mx = -1e30f;
            #pragma unroll
            for (int j = 0; j < 32; ++j) mx = fmaxf(mx, S[tid][j]);
            float sum = 0.0f;
            #pragma unroll
            for (int j = 0; j < 32; ++j) { float e = __expf(S[tid][j] - mx); S[tid][j] = e; sum += e; }
            float inv = 1.0f / sum;
            #pragma unroll
            for (int j = 0; j < 32; ++j) S[tid][j] *= inv;
        }
        __syncthreads();
        short8 ov;
        #pragma unroll
        for (int cc = 0; cc < 8; ++cc) {
            float acc = 0.0f;
            #pragma unroll
            for (int j = 0; j < 32; ++j) acc += S[i][j] * Vs[j][c0 + cc];
            ov[cc] = (short)f2bf(acc);
        }
        *(short8*)(p.o + (size_t)gn * DIM + hh * DKH + c0) = ov;
        __syncthreads();
    }
}

// ---------------------------------------------------------------- last-layer attention (256 thr)
__device__ void stage_attn_last(const MP& p, char* smem)
{
    float (*Ks)[65] = (float(*)[65])(smem);
    float (*Vs)[65] = (float(*)[65])(smem + 8320);
    float* Qs = (float*)(smem + 16640);     // 64
    float* Pp = Qs + 64;                    // 32
    int tid = threadIdx.x;
    int j = tid >> 3;
    int c0 = (tid & 7) * 8;
    for (int u = blockIdx.x; u < NG * NHD; u += GRID) {
        int g = u >> 3, hh = u & 7;
        __syncthreads();
        int gn = (j < NP) ? g * NP + j : NORI + g;
        const unsigned short* kb = p.qkv + (size_t)gn * 1536 + hh * DKH;
        short8 k8 = *(const short8*)(kb + 512 + c0);
        short8 v8 = *(const short8*)(kb + 1024 + c0);
        #pragma unroll
        for (int t = 0; t < 8; ++t) {
            Ks[j][c0 + t] = bf2f((unsigned short)k8[t]);
            Vs[j][c0 + t] = bf2f((unsigned short)v8[t]);
        }
        if (tid < 64) Qs[tid] = bf2f(p.qkv[(size_t)(NORI + g) * 1536 + hh * DKH + tid]);
        __syncthreads();
        if (tid < 64) {
            float s;
            if (tid < 32) {
                float dot = 0.0f;
                #pragma unroll
                for (int k = 0; k < 64; ++k) dot += Qs[k] * Ks[tid][k];
                s = dot * 0.125f + p.Bg[(size_t)g * 1024 + 31 * 32 + tid];
            } else s = -1e30f;
            float mx = s;
            #pragma unroll
            for (int off = 32; off > 0; off >>= 1) mx = fmaxf(mx, __shfl_xor(mx, off));
            float e = (tid < 32) ? __expf(s - mx) : 0.0f;
            float sum = e;
            #pragma unroll
            for (int off = 32; off > 0; off >>= 1) sum += __shfl_xor(sum, off);
            if (tid < 32) Pp[tid] = e / sum;
        }
        __syncthreads();
        if (tid < 64) {
            float acc = 0.0f;
            #pragma unroll
            for (int jj = 0; jj < 32; ++jj) acc += Pp[jj] * Vs[jj][tid];
            p.o[(size_t)(NORI + g) * DIM + hh * DKH + tid] = f2bf(acc);
        }
        __syncthreads();
    }
}

// ---------------------------------------------------------------- mega kernel
__global__ __launch_bounds__(256, 2) void mega(MP p)
{
    __shared__ __align__(16) char smem[32768];

    // stage 0: prep (init_h+B, QKV weight transpose, Wo/W1/W2 transpose)
    for (int u = blockIdx.x; u < 2112 + 3096 + 9216; u += GRID) {
        __syncthreads();
        if (u < 2112)      prep_inith_unit(p, u, smem);
        else if (u < 5208) prep_qkv_unit(p, u - 2112, smem);
        else               prep_w_unit(p, u - 5208, smem);
    }
    gbar(p.bar);

    for (int l = 0; l < NLAY; ++l) {
        const bool last = (l == NLAY - 1);
        stage_ln(p, 0, NT, false, smem);
        gbar(p.bar);
        stage_gemm128(p.hn, p.Wqkv_t + (size_t)l * 1536 * DIM, p.bqkv + l * 1536,
                      p.qkv, 1536, DIM, last ? 6 : 2, 16, 12, 1, smem);
        gbar(p.bar);
        if (!last) stage_attn(p, smem);
        else       stage_attn_last(p, smem);
        gbar(p.bar);
        if (!last)
            stage_gemm128(p.o, p.Wo_t + (size_t)l * DIM * DIM, p.bo + l * DIM,
                          p.h, DIM, DIM, 0, 16, 4, 2, smem);
        else
            stage_gemm64(p.o, p.Wo_t + (size_t)l * DIM * DIM, p.bo + l * DIM,
                         p.h, DIM, DIM, NORI, 0, 1, 8, 8, 0, smem);
        gbar(p.bar);
        stage_ln(p, last ? NORI : 0, last ? NG : NT, last, smem);
        gbar(p.bar);
        if (!last)
            stage_gemm128(p.hn, p.W1_t + (size_t)l * FFD * DIM, p.b1 + l * FFD,
                          p.qkv, FFD, DIM, 3, 16, 16, 1, smem);
        else
            stage_gemm64(p.hn, p.W1_t + (size_t)l * FFD * DIM, p.b1 + l * FFD,
                         p.qkv, FFD, DIM, NORI, 3, 1, 32, 1, 0, smem);
        gbar(p.bar);
        if (!last)
            stage_gemm128(p.qkv, p.W2_t + (size_t)l * DIM * FFD, p.b2 + l * DIM,
                          p.h, DIM, FFD, 0, 16, 4, 4, smem);
        else
            stage_gemm64(p.qkv, p.W2_t + (size_t)l * DIM * FFD, p.b2 + l * DIM,
                         p.out, DIM, FFD, NORI, 0, 1, 8, 8, NORI, smem);
        if (!last) gbar(p.bar);
    }
}

// ---------------------------------------------------------------- launch
extern "C" void kernel_launch(void* const* d_in, const int* in_sizes, int n_in,
                              void* d_out, int out_size, void* d_ws, size_t ws_size,
                              hipStream_t stream)
{
    MP p;
    p.x        = (const float*)d_in[0];
    p.sp       = (const int*)d_in[1];
    p.degrees  = (const int*)d_in[3];
    p.init_W   = (const float*)d_in[4];
    p.init_b   = (const float*)d_in[5];
    p.cent_emb = (const float*)d_in[6];
    p.db       = (const float*)d_in[7];
    p.vbias    = (const float*)d_in[8];
    p.Wq       = (const float*)d_in[9];
    p.bq       = (const float*)d_in[10];
    p.Wk       = (const float*)d_in[11];
    p.bk       = (const float*)d_in[12];
    p.Wv       = (const float*)d_in[13];
    p.bv       = (const float*)d_in[14];
    p.Wo       = (const float*)d_in[15];
    p.bo       = (const float*)d_in[16];
    p.W1       = (const float*)d_in[17];
    p.b1       = (const float*)d_in[18];
    p.W2       = (const float*)d_in[19];
    p.b2       = (const float*)d_in[20];

    char* ws = (char*)d_ws;
    p.h      = (float*)ws;          ws += (size_t)NT * DIM * 4;
    p.hn     = (unsigned short*)ws; ws += (size_t)NT * DIM * 2;
    p.o      = (unsigned short*)ws; ws += (size_t)NT * DIM * 2;
    p.qkv    = (unsigned short*)ws; ws += (size_t)NT * FFD * 2;      // aliased qkv/ffn
    p.Bg     = (float*)ws;          ws += (size_t)NG * 1024 * 4;
    p.Wqkv_t = (unsigned short*)ws; ws += (size_t)NLAY * 1536 * DIM * 2;
    p.Wo_t   = (unsigned short*)ws; ws += (size_t)NLAY * DIM * DIM * 2;
    p.W1_t   = (unsigned short*)ws; ws += (size_t)NLAY * FFD * DIM * 2;
    p.W2_t   = (unsigned short*)ws; ws += (size_t)NLAY * DIM * FFD * 2;
    p.bqkv   = (float*)ws;          ws += (size_t)NLAY * 1536 * 4;
    p.bar    = (unsigned*)ws;       ws += 256;
    p.out    = (float*)d_out;

    bar_init<<<1, 64, 0, stream>>>(p.bar);
    mega<<<GRID, 256, 0, stream>>>(p);
}

// Round 4
// 719.737 us; speedup vs baseline: 4.0882x; 4.0882x over previous
//
#include <hip/hip_runtime.h>

// Graphormer encoder — single persistent mega-kernel, hierarchical grid barrier.
// R12: R11's barrier was the regression (acquire-loads in the spin loop ->
// per-poll L2 invalidates -> 90us/barrier + 266MB refetch). New barrier:
// monotonic 2-level counters (16 groups x 16 blocks, 128B-separated lines),
// RELAXED polls, exactly one release fence before arrival and one acquire
// fence after release is observed. GRID=256 (1 block/CU, trivially resident).

#define NG   64
#define NP   31
#define NORI 1984
#define NT   2048
#define DIM  512
#define NHD  8
#define DKH  64
#define FFD  2048
#define NLAY 4
#define NFEA 32
#define GRID 256
#define GSH  4          // log2(group size) = 16 blocks/group, 16 groups

typedef __attribute__((ext_vector_type(8))) short short8;
typedef __attribute__((ext_vector_type(4))) float floatx4;

__device__ __forceinline__ unsigned short f2bf(float f) {
    union { float f; unsigned u; } v; v.f = f;
    unsigned r = v.u + 0x7fffu + ((v.u >> 16) & 1u);
    return (unsigned short)(r >> 16);
}
__device__ __forceinline__ float bf2f(unsigned short u) {
    union { unsigned u; float f; } v; v.u = ((unsigned)u) << 16;
    return v.f;
}

struct MP {
    const float* x; const int* sp; const int* degrees;
    const float* init_W; const float* init_b; const float* cent_emb;
    const float* db; const float* vbias;
    const float* Wq; const float* Wk; const float* Wv;
    const float* bq; const float* bk; const float* bv;
    const float* Wo; const float* bo; const float* W1; const float* b1;
    const float* W2; const float* b2;
    float* h; unsigned short* hn; unsigned short* o; unsigned short* qkv;
    float* Bg;
    unsigned short* Wqkv_t; unsigned short* Wo_t; unsigned short* W1_t; unsigned short* W2_t;
    float* bqkv;
    unsigned* bar;
    float* out;
};

// ---------------------------------------------------------------- grid barrier
// Layout: group g (g<16): bar[g*32] = leaf cnt (monotonic). bar[512] = root cnt.
// bar[g*32+1] = leaf gen, bar[513]... root gen at bar[512+1]? keep lines apart:
// root cnt = bar[16*32], root gen = bar[16*32+1]. All monotonic; epoch e target 16e.
__device__ __forceinline__ void gbar(unsigned* bar, unsigned e)
{
    __syncthreads();                               // drains this block's vmem
    if (threadIdx.x == 0) {
        __builtin_amdgcn_fence(__ATOMIC_RELEASE, "agent");      // writeback L2
        int g = blockIdx.x >> GSH;
        unsigned* leafc = bar + g * 32;
        unsigned* leafg = bar + g * 32 + 1;
        unsigned* rootc = bar + 16 * 32;
        unsigned* rootg = bar + 16 * 32 + 1;
        unsigned t = __hip_atomic_fetch_add(leafc, 1u, __ATOMIC_RELAXED,
                                            __HIP_MEMORY_SCOPE_AGENT) + 1u;
        if (t == (e << GSH)) {                     // last of 16 in group
            unsigned r = __hip_atomic_fetch_add(rootc, 1u, __ATOMIC_RELAXED,
                                                __HIP_MEMORY_SCOPE_AGENT) + 1u;
            if (r == (e << 4)) {                   // last of 16 groups
                __hip_atomic_fetch_add(rootg, 1u, __ATOMIC_RELAXED,
                                       __HIP_MEMORY_SCOPE_AGENT);
            } else {
                while (__hip_atomic_load(rootg, __ATOMIC_RELAXED,
                                         __HIP_MEMORY_SCOPE_AGENT) < e)
                    __builtin_amdgcn_s_sleep(1);
            }
            __hip_atomic_fetch_add(leafg, 1u, __ATOMIC_RELAXED,
                                   __HIP_MEMORY_SCOPE_AGENT);
        } else {
            while (__hip_atomic_load(leafg, __ATOMIC_RELAXED,
                                     __HIP_MEMORY_SCOPE_AGENT) < e)
                __builtin_amdgcn_s_sleep(1);
        }
        __builtin_amdgcn_fence(__ATOMIC_ACQUIRE, "agent");      // invalidate
    }
    __syncthreads();
}

__global__ void bar_init(unsigned* bar) {
    for (int i = threadIdx.x; i < 1024; i += 256) bar[i] = 0u;
}

// ---------------------------------------------------------------- prep units
__device__ __forceinline__ void prep_inith_unit(const MP& p, int n, char* smem)
{
    int tid = threadIdx.x;
    if (n >= NT) {               // build_B: one unit per graph
        int g = n - NT;
        float vb = p.vbias[0];
        for (int e = tid; e < 1024; e += 256) {
            int i = e >> 5, j = e & 31;
            float v;
            if (i == j) v = p.db[0];
            else if (i < NP && j < NP) {
                int s = p.sp[(size_t)(g * NP + i) * NORI + g * NP + j];
                v = p.db[s < 100 ? s : 100];
            } else v = vb;
            p.Bg[(size_t)g * 1024 + e] = v;
        }
        return;
    }
    float* xs = (float*)smem;
    if (n < NORI && tid < NFEA) xs[tid] = p.x[(size_t)n * NFEA + tid];
    __syncthreads();
    int deg = p.degrees[n]; if (deg > 100) deg = 100;
    for (int d = tid; d < DIM; d += 256) {
        float v = p.cent_emb[(size_t)deg * DIM + d];
        if (n < NORI) {
            float acc = p.init_b[d];
            #pragma unroll
            for (int k = 0; k < NFEA; ++k) acc += xs[k] * p.init_W[(size_t)k * DIM + d];
            v += acc;
        }
        p.h[(size_t)n * DIM + d] = v;
    }
}

__device__ __forceinline__ void prep_qkv_unit(const MP& p, int tile, char* smem)
{
    if (tile >= 3072) {          // bias part
        int idx = (tile - 3072) * 256 + threadIdx.x;
        if (idx < NLAY * 1536) {
            int l = idx / 1536, c = idx % 1536;
            int which = c >> 9, cc = c & 511;
            const float* b = (which == 0) ? p.bq : (which == 1) ? p.bk : p.bv;
            p.bqkv[idx] = b[(size_t)l * 512 + cc];
        }
        return;
    }
    float (*tl)[33] = (float(*)[33])smem;
    int slice = tile >> 5;
    int tloc = tile & 31;
    int dt = tloc >> 1, kt = tloc & 1;
    int l = slice / 24; int rem = slice % 24; int which = rem >> 3; int hh = rem & 7;
    const float* W = (which == 0) ? p.Wq : (which == 1) ? p.Wk : p.Wv;
    const float* in = W + (size_t)(l * 8 + hh) * DIM * DKH;
    int tr = threadIdx.x >> 5, tc = threadIdx.x & 31;
    #pragma unroll
    for (int pp = 0; pp < 4; ++pp)
        tl[tr + pp * 8][tc] = in[(size_t)(dt * 32 + tr + pp * 8) * DKH + kt * 32 + tc];
    __syncthreads();
    unsigned short* out = p.Wqkv_t + ((size_t)l * 1536 + which * 512 + hh * 64 + kt * 32) * DIM + dt * 32;
    #pragma unroll
    for (int pp = 0; pp < 4; ++pp)
        out[(size_t)(tr + pp * 8) * DIM + tc] = f2bf(tl[tc][tr + pp * 8]);
}

__device__ __forceinline__ void prep_w_unit(const MP& p, int id, char* smem)
{
    float (*tl)[33] = (float(*)[33])smem;
    const float* in; unsigned short* outp; int R, C, l, rt, ct;
    if (id < 1024) {
        l = id >> 8; int t = id & 255; rt = t >> 4; ct = t & 15;
        in = p.Wo; outp = p.Wo_t; R = 512; C = 512;
    } else if (id < 5120) {
        int t2 = id - 1024; l = t2 >> 10; int t = t2 & 1023; rt = t >> 6; ct = t & 63;
        in = p.W1; outp = p.W1_t; R = 512; C = 2048;
    } else {
        int t2 = id - 5120; l = t2 >> 10; int t = t2 & 1023; rt = t >> 4; ct = t & 15;
        in = p.W2; outp = p.W2_t; R = 2048; C = 512;
    }
    const float* ip = in + (size_t)l * R * C;
    unsigned short* op = outp + (size_t)l * R * C;
    int r0 = rt * 32, c0 = ct * 32;
    int tr = threadIdx.x >> 5, tc = threadIdx.x & 31;
    #pragma unroll
    for (int pp = 0; pp < 4; ++pp)
        tl[tr + pp * 8][tc] = ip[(size_t)(r0 + tr + pp * 8) * C + c0 + tc];
    __syncthreads();
    #pragma unroll
    for (int pp = 0; pp < 4; ++pp)
        op[(size_t)(c0 + tr + pp * 8) * R + r0 + tc] = f2bf(tl[tc][tr + pp * 8]);
}

// ---------------------------------------------------------------- layernorm stage
__device__ void stage_ln(const MP& p, int row0, int nrows, bool docopy, char* smem)
{
    float* red = (float*)smem;
    int tid = threadIdx.x;
    int wave = tid >> 6;
    for (int r = blockIdx.x; r < nrows; r += GRID) {
        int n = row0 + r;
        const float* row = p.h + (size_t)n * DIM;
        float v0 = row[tid], v1 = row[tid + 256];
        float s = v0 + v1;
        float sq = v0 * v0 + v1 * v1;
        #pragma unroll
        for (int off = 32; off > 0; off >>= 1) {
            s  += __shfl_down(s, off);
            sq += __shfl_down(sq, off);
        }
        if ((tid & 63) == 0) { red[wave] = s; red[4 + wave] = sq; }
        __syncthreads();
        float ts  = red[0] + red[1] + red[2] + red[3];
        float tsq = red[4] + red[5] + red[6] + red[7];
        __syncthreads();                      // red reused next iteration
        float m   = ts * (1.0f / DIM);
        float var = tsq * (1.0f / DIM) - m * m;
        float inv = rsqrtf(var + 1e-5f);
        p.hn[(size_t)n * DIM + tid]       = f2bf((v0 - m) * inv);
        p.hn[(size_t)n * DIM + tid + 256] = f2bf((v1 - m) * inv);
        if (docopy) {                         // seed d_out with the residual h
            p.out[(size_t)(n - NORI) * DIM + tid]       = v0;
            p.out[(size_t)(n - NORI) * DIM + tid + 256] = v1;
        }
    }
}

// ---------------------------------------------------------------- gemm128 stage (m97 structure)
__device__ void stage_gemm128(const unsigned short* __restrict__ A,
    const unsigned short* __restrict__ Bt, const float* __restrict__ bias,
    void* __restrict__ out, int Nfull, int K, int flags, int P, int C,
    int SPLITK, char* smem)
{
    unsigned short* Asl = (unsigned short*)smem;
    unsigned short* Bsl = Asl + 128 * 64;
    int ntiles = P * C * SPLITK;
    int tid = threadIdx.x;
    int wave = tid >> 6, lane = tid & 63;
    int quad = lane >> 4, m16 = lane & 15;
    int mw = (wave >> 1) * 64, nw = (wave & 1) * 64;
    int lr = lane >> 3;
    int srcswz = ((lane & 7) ^ lr) << 3;
    int rdswz = (m16 & 7) << 4;
    int kslice = K / SPLITK;
    for (int id = blockIdx.x; id < ntiles; id += GRID) {
        int xcd = id & 7, t = id >> 3, Gp = P >> 3;
        int by = xcd + 8 * (t % Gp);
        int r2 = t / Gp;
        int bx = r2 % C;
        int bz = r2 / C;
        int row0 = by * 128, col0 = bx * 128;
        if ((flags & 4) && col0 < 512 && row0 + 128 <= NORI) continue;
        int kbeg = bz * kslice;
        const unsigned short* Abase = A + (size_t)row0 * K;
        const unsigned short* Bbase = Bt + (size_t)col0 * K;
        floatx4 acc[4][4] = {};
        __syncthreads();
        for (int k0 = kbeg; k0 < kbeg + kslice; k0 += 64) {
            #pragma unroll
            for (int pp = 0; pp < 4; ++pp) {
                int chunk = wave * 4 + pp;
                int r = chunk * 8 + lr;
                __builtin_amdgcn_global_load_lds(
                    (const __attribute__((address_space(1))) unsigned int*)
                        (Abase + (size_t)r * K + k0 + srcswz),
                    (__attribute__((address_space(3))) unsigned int*)
                        (Asl + chunk * 512 + lane * 8), 16, 0, 0);
                __builtin_amdgcn_global_load_lds(
                    (const __attribute__((address_space(1))) unsigned int*)
                        (Bbase + (size_t)r * K + k0 + srcswz),
                    (__attribute__((address_space(3))) unsigned int*)
                        (Bsl + chunk * 512 + lane * 8), 16, 0, 0);
            }
            __syncthreads();
            #pragma unroll
            for (int ks = 0; ks < 64; ks += 32) {
                short8 a[4], b[4];
                int cb = (ks + quad * 8) * 2;
                #pragma unroll
                for (int mi = 0; mi < 4; ++mi)
                    a[mi] = *(const short8*)((const char*)Asl +
                            (mw + mi * 16 + m16) * 128 + (cb ^ rdswz));
                #pragma unroll
                for (int ni = 0; ni < 4; ++ni)
                    b[ni] = *(const short8*)((const char*)Bsl +
                            (nw + ni * 16 + m16) * 128 + (cb ^ rdswz));
                #pragma unroll
                for (int mi = 0; mi < 4; ++mi)
                    #pragma unroll
                    for (int ni = 0; ni < 4; ++ni)
                        acc[mi][ni] = __builtin_amdgcn_mfma_f32_16x16x32_bf16(
                            a[mi], b[ni], acc[mi][ni], 0, 0, 0);
            }
            __syncthreads();
        }
        if (SPLITK == 1) {
            int do_relu = flags & 1, out_bf = flags & 2;
            #pragma unroll
            for (int mi = 0; mi < 4; ++mi) {
                #pragma unroll
                for (int ni = 0; ni < 4; ++ni) {
                    int col = col0 + nw + ni * 16 + m16;
                    float bval = bias[col];
                    #pragma unroll
                    for (int rr = 0; rr < 4; ++rr) {
                        int row = row0 + mw + mi * 16 + quad * 4 + rr;
                        float v = acc[mi][ni][rr] + bval;
                        if (do_relu) v = fmaxf(v, 0.0f);
                        if (out_bf) ((unsigned short*)out)[(size_t)row * Nfull + col] = f2bf(v);
                        else        ((float*)out)[(size_t)row * Nfull + col] = v;
                    }
                }
            }
        } else {
            float* ofp = (float*)out;
            float bscale = (bz == 0) ? 1.0f : 0.0f;
            #pragma unroll
            for (int mi = 0; mi < 4; ++mi) {
                #pragma unroll
                for (int ni = 0; ni < 4; ++ni) {
                    int col = col0 + nw + ni * 16 + m16;
                    float bval = bias[col] * bscale;
                    #pragma unroll
                    for (int rr = 0; rr < 4; ++rr) {
                        int row = row0 + mw + mi * 16 + quad * 4 + rr;
                        atomicAdd(&ofp[(size_t)row * Nfull + col], acc[mi][ni][rr] + bval);
                    }
                }
            }
        }
    }
}

// ---------------------------------------------------------------- gemm64 stage (small M)
__device__ void stage_gemm64(const unsigned short* __restrict__ A,
    const unsigned short* __restrict__ Bt, const float* __restrict__ bias,
    void* __restrict__ out, int Nfull, int K, int moff, int flags,
    int P, int C, int SPLITK, int orow, char* smem)
{
    unsigned short* Asl = (unsigned short*)smem;          // 64*72
    unsigned short* Bsl = Asl + 64 * 72;
    int ntiles = P * C * SPLITK;
    int tid = threadIdx.x;
    int wave = tid >> 6, lane = tid & 63;
    int quad = lane >> 4, m16 = lane & 15;
    int mw = (wave >> 1) * 32, nw = (wave & 1) * 32;
    int kslice = K / SPLITK;
    for (int id = blockIdx.x; id < ntiles; id += GRID) {
        int by, bx, bz;
        if (P >= 8) {
            int xcd = id & 7, t = id >> 3, Gp = P >> 3;
            by = xcd + 8 * (t % Gp);
            int r2 = t / Gp;
            bx = r2 % C;
            bz = r2 / C;
        } else {
            by = id % P; int r2 = id / P; bx = r2 % C; bz = r2 / C;
        }
        int row0 = moff + by * 64, col0 = bx * 64;
        if ((flags & 4) && col0 < 512 && row0 < NORI) continue;
        int kbeg = bz * kslice;
        floatx4 acc[2][2] = {};
        __syncthreads();
        for (int k0 = kbeg; k0 < kbeg + kslice; k0 += 64) {
            #pragma unroll
            for (int pp = 0; pp < 2; ++pp) {
                int idx = (pp * 256 + tid) * 8;
                int r = idx >> 6, kk = idx & 63;
                *(float4*)(Asl + r * 72 + kk) =
                    *(const float4*)(A + (size_t)(row0 + r) * K + k0 + kk);
                *(float4*)(Bsl + r * 72 + kk) =
                    *(const float4*)(Bt + (size_t)(col0 + r) * K + k0 + kk);
            }
            __syncthreads();
            #pragma unroll
            for (int ks = 0; ks < 64; ks += 32) {
                short8 a[2], b[2];
                #pragma unroll
                for (int mi = 0; mi < 2; ++mi)
                    a[mi] = *(const short8*)(Asl + (mw + mi * 16 + m16) * 72 + ks + quad * 8);
                #pragma unroll
                for (int ni = 0; ni < 2; ++ni)
                    b[ni] = *(const short8*)(Bsl + (nw + ni * 16 + m16) * 72 + ks + quad * 8);
                #pragma unroll
                for (int mi = 0; mi < 2; ++mi)
                    #pragma unroll
                    for (int ni = 0; ni < 2; ++ni)
                        acc[mi][ni] = __builtin_amdgcn_mfma_f32_16x16x32_bf16(
                            a[mi], b[ni], acc[mi][ni], 0, 0, 0);
            }
            __syncthreads();
        }
        if (SPLITK == 1) {
            int do_relu = flags & 1, out_bf = flags & 2;
            #pragma unroll
            for (int mi = 0; mi < 2; ++mi) {
                #pragma unroll
                for (int ni = 0; ni < 2; ++ni) {
                    int col = col0 + nw + ni * 16 + m16;
                    float bval = bias[col];
                    #pragma unroll
                    for (int rr = 0; rr < 4; ++rr) {
                        int row = row0 + mw + mi * 16 + quad * 4 + rr;
                        float v = acc[mi][ni][rr] + bval;
                        if (do_relu) v = fmaxf(v, 0.0f);
                        if (out_bf) ((unsigned short*)out)[(size_t)(row - orow) * Nfull + col] = f2bf(v);
                        else        ((float*)out)[(size_t)(row - orow) * Nfull + col] = v;
                    }
                }
            }
        } else {
            float* ofp = (float*)out;
            float bscale = (bz == 0) ? 1.0f : 0.0f;
            #pragma unroll
            for (int mi = 0; mi < 2; ++mi) {
                #pragma unroll
                for (int ni = 0; ni < 2; ++ni) {
                    int col = col0 + nw + ni * 16 + m16;
                    float bval = bias[col] * bscale;
                    #pragma unroll
                    for (int rr = 0; rr < 4; ++rr) {
                        int row = row0 + mw + mi * 16 + quad * 4 + rr;
                        atomicAdd(&ofp[(size_t)(row - orow) * Nfull + col],
                                  acc[mi][ni][rr] + bval);
                    }
                }
            }
        }
    }
}

// ---------------------------------------------------------------- attention stage (layers 0..2)
__device__ void stage_attn(const MP& p, char* smem)
{
    float (*Qs)[65] = (float(*)[65])(smem);
    float (*Ks)[65] = (float(*)[65])(smem + 8320);
    float (*Vs)[65] = (float(*)[65])(smem + 16640);
    float (*S)[33]  = (float(*)[33])(smem + 24960);
    int tid = threadIdx.x;
    int i = tid >> 3;
    int c0 = (tid & 7) * 8;
    for (int u = blockIdx.x; u < NG * NHD; u += GRID) {
        int g = u >> 3, hh = u & 7;
        __syncthreads();
        int gn = (i < NP) ? g * NP + i : NORI + g;
        const unsigned short* base = p.qkv + (size_t)gn * 1536 + hh * DKH;
        short8 qv = *(const short8*)(base + c0);
        short8 kv = *(const short8*)(base + 512 + c0);
        short8 vv = *(const short8*)(base + 1024 + c0);
        #pragma unroll
        for (int j = 0; j < 8; ++j) {
            Qs[i][c0 + j] = bf2f((unsigned short)qv[j]);
            Ks[i][c0 + j] = bf2f((unsigned short)kv[j]);
            Vs[i][c0 + j] = bf2f((unsigned short)vv[j]);
        }
        __syncthreads();
        const float scale = 0.125f;
        #pragma unroll
        for (int e = 0; e < 4; ++e) {
            int idx = tid + e * 256;
            int si = idx >> 5, sj = idx & 31;
            float dot = 0.0f;
            #pragma unroll
            for (int k = 0; k < DKH; ++k) dot += Qs[si][k] * Ks[sj][k];
            S[si][sj] = dot * scale + p.Bg[(size_t)g * 1024 + si * 32 + sj];
        }
        __syncthreads();
        if (tid < 32) {
            float mx = -1e30f;
            #pragma unroll
            for (int j = 0; j < 32; ++j) mx = fmaxf(mx, S[tid][j]);
            float sum = 0.0f;
            #pragma unroll
            for (int j = 0; j < 32; ++j) { float e = __expf(S[tid][j] - mx); S[tid][j] = e; sum += e; }
            float inv = 1.0f / sum;
            #pragma unroll
            for (int j = 0; j < 32; ++j) S[tid][j] *= inv;
        }
        __syncthreads();
        short8 ov;
        #pragma unroll
        for (int cc = 0; cc < 8; ++cc) {
            float acc = 0.0f;
            #pragma unroll
            for (int j = 0; j < 32; ++j) acc += S[i][j] * Vs[j][c0 + cc];
            ov[cc] = (short)f2bf(acc);
        }
        *(short8*)(p.o + (size_t)gn * DIM + hh * DKH + c0) = ov;
        __syncthreads();
    }
}

// ---------------------------------------------------------------- last-layer attention (256 thr)
__device__ void stage_attn_last(const MP& p, char* smem)
{
    float (*Ks)[65] = (float(*)[65])(smem);
    float (*Vs)[65] = (float(*)[65])(smem + 8320);
    float* Qs = (float*)(smem + 16640);     // 64
    float* Pp = Qs + 64;                    // 32
    int tid = threadIdx.x;
    int j = tid >> 3;
    int c0 = (tid & 7) * 8;
    for (int u = blockIdx.x; u < NG * NHD; u += GRID) {
        int g = u >> 3, hh = u & 7;
        __syncthreads();
        int gn = (j < NP) ? g * NP + j : NORI + g;
        const unsigned short* kb = p.qkv + (size_t)gn * 1536 + hh * DKH;
        short8 k8 = *(const short8*)(kb + 512 + c0);
        short8 v8 = *(const short8*)(kb + 1024 + c0);
        #pragma unroll
        for (int t = 0; t < 8; ++t) {
            Ks[j][c0 + t] = bf2f((unsigned short)k8[t]);
            Vs[j][c0 + t] = bf2f((unsigned short)v8[t]);
        }
        if (tid < 64) Qs[tid] = bf2f(p.qkv[(size_t)(NORI + g) * 1536 + hh * DKH + tid]);
        __syncthreads();
        if (tid < 64) {
            float s;
            if (tid < 32) {
                float dot = 0.0f;
                #pragma unroll
                for (int k = 0; k < 64; ++k) dot += Qs[k] * Ks[tid][k];
                s = dot * 0.125f + p.Bg[(size_t)g * 1024 + 31 * 32 + tid];
            } else s = -1e30f;
            float mx = s;
            #pragma unroll
            for (int off = 32; off > 0; off >>= 1) mx = fmaxf(mx, __shfl_xor(mx, off));
            float e = (tid < 32) ? __expf(s - mx) : 0.0f;
            float sum = e;
            #pragma unroll
            for (int off = 32; off > 0; off >>= 1) sum += __shfl_xor(sum, off);
            if (tid < 32) Pp[tid] = e / sum;
        }
        __syncthreads();
        if (tid < 64) {
            float acc = 0.0f;
            #pragma unroll
            for (int jj = 0; jj < 32; ++jj) acc += Pp[jj] * Vs[jj][tid];
            p.o[(size_t)(NORI + g) * DIM + hh * DKH + tid] = f2bf(acc);
        }
        __syncthreads();
    }
}

// ---------------------------------------------------------------- mega kernel
__global__ __launch_bounds__(256, 2) void mega(MP p)
{
    __shared__ __align__(16) char smem[32768];
    unsigned ep = 0;

    // stage 0: prep (init_h+B, QKV weight transpose, Wo/W1/W2 transpose)
    for (int u = blockIdx.x; u < 2112 + 3096 + 9216; u += GRID) {
        __syncthreads();
        if (u < 2112)      prep_inith_unit(p, u, smem);
        else if (u < 5208) prep_qkv_unit(p, u - 2112, smem);
        else               prep_w_unit(p, u - 5208, smem);
    }
    gbar(p.bar, ++ep);

    for (int l = 0; l < NLAY; ++l) {
        const bool last = (l == NLAY - 1);
        stage_ln(p, 0, NT, false, smem);
        gbar(p.bar, ++ep);
        stage_gemm128(p.hn, p.Wqkv_t + (size_t)l * 1536 * DIM, p.bqkv + l * 1536,
                      p.qkv, 1536, DIM, last ? 6 : 2, 16, 12, 1, smem);
        gbar(p.bar, ++ep);
        if (!last) stage_attn(p, smem);
        else       stage_attn_last(p, smem);
        gbar(p.bar, ++ep);
        if (!last)
            stage_gemm128(p.o, p.Wo_t + (size_t)l * DIM * DIM, p.bo + l * DIM,
                          p.h, DIM, DIM, 0, 16, 4, 4, smem);
        else
            stage_gemm64(p.o, p.Wo_t + (size_t)l * DIM * DIM, p.bo + l * DIM,
                         p.h, DIM, DIM, NORI, 0, 1, 8, 8, 0, smem);
        gbar(p.bar, ++ep);
        stage_ln(p, last ? NORI : 0, last ? NG : NT, last, smem);
        gbar(p.bar, ++ep);
        if (!last)
            stage_gemm128(p.hn, p.W1_t + (size_t)l * FFD * DIM, p.b1 + l * FFD,
                          p.qkv, FFD, DIM, 3, 16, 16, 1, smem);
        else
            stage_gemm64(p.hn, p.W1_t + (size_t)l * FFD * DIM, p.b1 + l * FFD,
                         p.qkv, FFD, DIM, NORI, 3, 1, 32, 1, 0, smem);
        gbar(p.bar, ++ep);
        if (!last)
            stage_gemm128(p.qkv, p.W2_t + (size_t)l * DIM * FFD, p.b2 + l * DIM,
                          p.h, DIM, FFD, 0, 16, 4, 4, smem);
        else
            stage_gemm64(p.qkv, p.W2_t + (size_t)l * DIM * FFD, p.b2 + l * DIM,
                         p.out, DIM, FFD, NORI, 0, 1, 8, 8, NORI, smem);
        if (!last) gbar(p.bar, ++ep);
    }
}

// ---------------------------------------------------------------- launch
extern "C" void kernel_launch(void* const* d_in, const int* in_sizes, int n_in,
                              void* d_out, int out_size, void* d_ws, size_t ws_size,
                              hipStream_t stream)
{
    MP p;
    p.x        = (const float*)d_in[0];
    p.sp       = (const int*)d_in[1];
    p.degrees  = (const int*)d_in[3];
    p.init_W   = (const float*)d_in[4];
    p.init_b   = (const float*)d_in[5];
    p.cent_emb = (const float*)d_in[6];
    p.db       = (const float*)d_in[7];
    p.vbias    = (const float*)d_in[8];
    p.Wq       = (const float*)d_in[9];
    p.bq       = (const float*)d_in[10];
    p.Wk       = (const float*)d_in[11];
    p.bk       = (const float*)d_in[12];
    p.Wv       = (const float*)d_in[13];
    p.bv       = (const float*)d_in[14];
    p.Wo       = (const float*)d_in[15];
    p.bo       = (const float*)d_in[16];
    p.W1       = (const float*)d_in[17];
    p.b1       = (const float*)d_in[18];
    p.W2       = (const float*)d_in[19];
    p.b2       = (const float*)d_in[20];

    char* ws = (char*)d_ws;
    p.h      = (float*)ws;          ws += (size_t)NT * DIM * 4;
    p.hn     = (unsigned short*)ws; ws += (size_t)NT * DIM * 2;
    p.o      = (unsigned short*)ws; ws += (size_t)NT * DIM * 2;
    p.qkv    = (unsigned short*)ws; ws += (size_t)NT * FFD * 2;      // aliased qkv/ffn
    p.Bg     = (float*)ws;          ws += (size_t)NG * 1024 * 4;
    p.Wqkv_t = (unsigned short*)ws; ws += (size_t)NLAY * 1536 * DIM * 2;
    p.Wo_t   = (unsigned short*)ws; ws += (size_t)NLAY * DIM * DIM * 2;
    p.W1_t   = (unsigned short*)ws; ws += (size_t)NLAY * FFD * DIM * 2;
    p.W2_t   = (unsigned short*)ws; ws += (size_t)NLAY * DIM * FFD * 2;
    p.bqkv   = (float*)ws;          ws += (size_t)NLAY * 1536 * 4;
    p.bar    = (unsigned*)ws;       ws += 4096;
    p.out    = (float*)d_out;

    bar_init<<<1, 256, 0, stream>>>(p.bar);
    mega<<<GRID, 256, 0, stream>>>(p);
}